// Round 17
// baseline (294.772 us; speedup 1.0000x reference)
//
#include <hip/hip_runtime.h>

#define N_NODES 200000
#define N_EDGES 3200000
#define N_GRAPHS 1024
#define HD 16
#define ALPHA_ 0.2f

#define BNODES 512                 // nodes per bucket (dst >> 9)
#define NBUCK 391                  // ceil(N_NODES/512)
#define CHUNKA 8192                // edges per bucket-pass block (1024 thr x 2 x int4)
#define NBLKA 391                  // ceil(N_EDGES/8192)
#define CAP 9216                   // padded bucket capacity (mean 8192, sigma~90, +11 sigma)

#define EA_DEC 6.103515625e-05f    // 1/16384 — 14-bit fixed-point ea decode

typedef unsigned long long u64;
typedef unsigned int u32;
typedef _Float16 f16;

// ---------- single-pass bucketing ----------
// R9 (keeper): entries locally counting-sorted by bucket-id into a 64 KB LDS
// stage, then each ~21-entry run written with CONSECUTIVE lanes.
// R11: shfl_up wave scan (2 barriers); half-wave write-out granularity.
// bucketedP entry = (ea:f32 | dlow:9 | src:18)  (full-precision ea kept here
// because sortd's degree sums need it).
__global__ __launch_bounds__(1024) void bucket_kernel(const int* __restrict__ src,
                                                      const int* __restrict__ dst,
                                                      const float* __restrict__ ea,
                                                      int* __restrict__ gcursor,
                                                      u64* __restrict__ bucketedP) {
    __shared__ int hist[NBUCK];
    __shared__ int lstart[NBUCK];
    __shared__ int lcur[NBUCK];
    __shared__ int gbase[NBUCK];
    __shared__ int sincl[512];
    __shared__ int wsum[8];
    __shared__ u64 stage[CHUNKA];        // 64 KB; total ~72 KB -> 2 blocks/CU
    int t = threadIdx.x;
    if (t < NBUCK) hist[t] = 0;
    __syncthreads();
    int e0 = blockIdx.x * CHUNKA;
    int e1 = min(e0 + CHUNKA, N_EDGES);
    int ia = e0 + (t << 2);
    int ib = e0 + 4096 + (t << 2);
    bool va = ia < e1, vb = ib < e1;
    int4 d4a, d4b;
    if (va) {   // edges multiple of 4 -> full int4 valid; dst held in regs for pass 2
        d4a = *(const int4*)(dst + ia);
        atomicAdd(&hist[d4a.x >> 9], 1);
        atomicAdd(&hist[d4a.y >> 9], 1);
        atomicAdd(&hist[d4a.z >> 9], 1);
        atomicAdd(&hist[d4a.w >> 9], 1);
    }
    if (vb) {
        d4b = *(const int4*)(dst + ib);
        atomicAdd(&hist[d4b.x >> 9], 1);
        atomicAdd(&hist[d4b.y >> 9], 1);
        atomicAdd(&hist[d4b.z >> 9], 1);
        atomicAdd(&hist[d4b.w >> 9], 1);
    }
    __syncthreads();
    // exclusive scan over 391 bins: shfl_up wave scan + 8-wavesum fixup
    int c = (t < NBUCK) ? hist[t] : 0;
    if (t < 512) {
        int lane = t & 63;
        int incl = c;
#pragma unroll
        for (int off = 1; off < 64; off <<= 1) {
            int v = __shfl_up(incl, off);
            if (lane >= off) incl += v;
        }
        sincl[t] = incl;
        if (lane == 63) wsum[t >> 6] = incl;
    }
    __syncthreads();
    if (t == 0) {
        int run = 0;
#pragma unroll
        for (int w = 0; w < 8; ++w) { int v = wsum[w]; wsum[w] = run; run += v; }
    }
    __syncthreads();
    if (t < NBUCK) {
        int ls = sincl[t] - c + wsum[t >> 6];
        lstart[t] = ls;
        lcur[t] = ls;
        gbase[t] = (c > 0) ? (t * CAP + atomicAdd(&gcursor[t], c)) : 0;
    }
    __syncthreads();
    // scatter into LDS stage, ordered by bucket
    if (va) {
        int4   s4 = *(const int4*)(src + ia);
        float4 a4 = *(const float4*)(ea + ia);
        int p0 = atomicAdd(&lcur[d4a.x >> 9], 1);
        int p1 = atomicAdd(&lcur[d4a.y >> 9], 1);
        int p2 = atomicAdd(&lcur[d4a.z >> 9], 1);
        int p3 = atomicAdd(&lcur[d4a.w >> 9], 1);
        stage[p0] = ((u64)__float_as_uint(a4.x) << 32) | (unsigned)(s4.x | ((d4a.x & 511) << 18));
        stage[p1] = ((u64)__float_as_uint(a4.y) << 32) | (unsigned)(s4.y | ((d4a.y & 511) << 18));
        stage[p2] = ((u64)__float_as_uint(a4.z) << 32) | (unsigned)(s4.z | ((d4a.z & 511) << 18));
        stage[p3] = ((u64)__float_as_uint(a4.w) << 32) | (unsigned)(s4.w | ((d4a.w & 511) << 18));
    }
    if (vb) {
        int4   s4 = *(const int4*)(src + ib);
        float4 a4 = *(const float4*)(ea + ib);
        int p0 = atomicAdd(&lcur[d4b.x >> 9], 1);
        int p1 = atomicAdd(&lcur[d4b.y >> 9], 1);
        int p2 = atomicAdd(&lcur[d4b.z >> 9], 1);
        int p3 = atomicAdd(&lcur[d4b.w >> 9], 1);
        stage[p0] = ((u64)__float_as_uint(a4.x) << 32) | (unsigned)(s4.x | ((d4b.x & 511) << 18));
        stage[p1] = ((u64)__float_as_uint(a4.y) << 32) | (unsigned)(s4.y | ((d4b.y & 511) << 18));
        stage[p2] = ((u64)__float_as_uint(a4.z) << 32) | (unsigned)(s4.z | ((d4b.z & 511) << 18));
        stage[p3] = ((u64)__float_as_uint(a4.w) << 32) | (unsigned)(s4.w | ((d4b.w & 511) << 18));
    }
    __syncthreads();
    // write-out: half-wave (32 lanes) per bucket -> two runs per wave store inst
    int hw = t >> 5, lane = t & 31;
    for (int u = hw; u < NBUCK; u += 32) {
        int c2 = hist[u];
        int ls = lstart[u];
        int gb = gbase[u];
        for (int k = lane; k < c2; k += 32)
            bucketedP[gb + k] = stage[ls + k];
    }
}

// in-bucket counting sort by dlow (9b) + fused degree (LDS f32 atomics).
// R12 (keeper): scanB fused — per-block compact base via shfl reduction.
// R14: u32 sorted entries = (ea_q14:14 | src:18).
// R16 (keeper): NO register array — bucketedP read twice (second pass L2-hot);
// live state in scatter loop = one u64 -> no spill at the 64-VGPR/1024-thr cap.
__global__ __launch_bounds__(1024) void sortd_kernel(const u64* __restrict__ bucketedP,
                                                     const int* __restrict__ gcursor,
                                                     const float* __restrict__ x,
                                                     u32* __restrict__ sorted,
                                                     int* __restrict__ nodeoff,
                                                     float* __restrict__ dinv,
                                                     float2* __restrict__ dx) {
    __shared__ int hist[512];
    __shared__ int cur[512];
    __shared__ float fdeg[512];
    __shared__ int sincl[512];
    __shared__ int wsum[8];
    __shared__ int wred[16];
    __shared__ int sb0;
    __shared__ u32 stage[CAP];          // 36 KB; total ~45 KB
    int u = blockIdx.x, t = threadIdx.x;
    if (t < 512) { hist[t] = 0; fdeg[t] = 0.f; }
    // compact base: b0 = sum of gcursor[0..u-1]  (16 waves cover 1024 slots)
    {
        int lane = t & 63, wv = t >> 6;
        int v = (t < u) ? gcursor[t] : 0;    // u <= 391 < 1024
#pragma unroll
        for (int off = 1; off < 64; off <<= 1) v += __shfl_xor(v, off);
        if (lane == 0) wred[wv] = v;
    }
    __syncthreads();
    if (t == 0) {
        int b = 0;
#pragma unroll
        for (int w = 0; w < 16; ++w) b += wred[w];
        sb0 = b;
    }
    int m = gcursor[u];                  // bucket count (<= CAP)
    const u64* bp = bucketedP + (size_t)u * CAP;
    // pass 1: hist + weighted degree (full-precision ea)
    for (int i = t; i < m; i += 1024) {
        u64 ent = bp[i];
        int dl = (int)((ent >> 18) & 511u);
        atomicAdd(&hist[dl], 1);
        atomicAdd(&fdeg[dl], __uint_as_float((unsigned)(ent >> 32)));
    }
    __syncthreads();
    int b0 = sb0;
    // exclusive scan over 512 bins: shfl_up wave scan + 8-wavesum fixup
    int c = (t < 512) ? hist[t] : 0;
    if (t < 512) {
        int lane = t & 63;
        int incl = c;
#pragma unroll
        for (int off = 1; off < 64; off <<= 1) {
            int v = __shfl_up(incl, off);
            if (lane >= off) incl += v;
        }
        sincl[t] = incl;
        if (lane == 63) wsum[t >> 6] = incl;
    }
    __syncthreads();
    if (t == 0) {
        int run = 0;
#pragma unroll
        for (int w = 0; w < 8; ++w) { int v = wsum[w]; wsum[w] = run; run += v; }
    }
    __syncthreads();
    if (t < 512) {
        int excl = sincl[t] - c + wsum[t >> 6];   // bucket-local exclusive
        cur[t] = excl;
        int n = u * BNODES + t;
        if (n < N_NODES) {
            nodeoff[n] = b0 + excl;
            float dn = rsqrtf(fdeg[t] + 1.0f);
            dinv[n] = dn;
            dx[n] = make_float2(dn, dn * x[n]);
        }
    }
    __syncthreads();
    // pass 2: re-read (L2-hot), quantize ea -> 14-bit, scatter u32 into LDS
    for (int i = t; i < m; i += 1024) {
        u64 ent = bp[i];
        int pos = atomicAdd(&cur[(int)((ent >> 18) & 511u)], 1);
        float eaf = __uint_as_float((unsigned)(ent >> 32));
        unsigned q = (unsigned)(eaf * 16384.0f);
        if (q > 16383u) q = 16383u;
        stage[pos] = (q << 18) | (u32)(ent & 0x3ffffu);
    }
    __syncthreads();
    for (int i = t; i < m; i += 1024)
        sorted[b0 + i] = stage[i];       // coalesced 4B stores
}

// layer 0: 4 threads/node (stride-4, 2 gathers in flight), 2-level shfl combine
__global__ __launch_bounds__(256) void agg0_kernel(const u32* __restrict__ sorted,
                                                   const int* __restrict__ nodeoff,
                                                   const float2* __restrict__ dx,
                                                   float2* __restrict__ db0,
                                                   float* __restrict__ s1v) {
    int t = threadIdx.x;
    int n = blockIdx.x * 64 + (t >> 2);   // 3125 * 64 = 200000 exactly
    int h = t & 3;
    float acc = 0.f, wsum = 0.f;
    {
        int e0 = nodeoff[n];
        int e1 = (n < N_NODES - 1) ? nodeoff[n + 1] : N_EDGES;
        int i = e0 + h;
        for (; i + 4 < e1; i += 8) {
            u32 en0 = sorted[i], en1 = sorted[i + 4];
            float2 g0 = dx[(int)(en0 & 0x3ffffu)];
            float2 g1 = dx[(int)(en1 & 0x3ffffu)];
            float a0 = ((float)(en0 >> 18) + 0.5f) * EA_DEC;
            float a1 = ((float)(en1 >> 18) + 0.5f) * EA_DEC;
            acc  += a0 * g0.y + a1 * g1.y;
            wsum += a0 * g0.x + a1 * g1.x;
        }
        if (i < e1) {
            u32 en = sorted[i];
            float2 g = dx[(int)(en & 0x3ffffu)];
            float a = ((float)(en >> 18) + 0.5f) * EA_DEC;
            acc += a * g.y;
            wsum += a * g.x;
        }
    }
    acc += __shfl_xor(acc, 1);
    wsum += __shfl_xor(wsum, 1);
    acc += __shfl_xor(acc, 2);
    wsum += __shfl_xor(wsum, 2);
    if (h == 0) {
        float2 d2 = dx[n];
        float dn = d2.x;
        float base0 = dn * acc + dn * d2.y;     // + dn^2 * x[n]
        db0[n] = make_float2(dn, base0);
        s1v[n] = dn * wsum + dn * dn;
    }
}

// layer 1: 4 threads/node edge phase (mirrors agg0), 2-level shfl combine, then
// 16-lane epilogue. fp16 h2hat out (R13 keeper; fp32 accumulation).
__global__ __launch_bounds__(256) void agg1_kernel(const u32* __restrict__ sorted,
                                                   const int* __restrict__ nodeoff,
                                                   const float2* __restrict__ db0,
                                                   const float* __restrict__ s1v,
                                                   const float* __restrict__ cw0,
                                                   const float* __restrict__ cb0,
                                                   const float* __restrict__ lw0,
                                                   const float* __restrict__ lb0,
                                                   const float* __restrict__ cwr0,
                                                   const float* __restrict__ cb1,
                                                   const float* __restrict__ lw1,
                                                   const float* __restrict__ lb1,
                                                   f16* __restrict__ h2hat) {
    __shared__ float sq[64 * 20];    // per node: q[16], c, dn, pad2  (5 KB)
    __shared__ float sa2[256];       // wave-local relu scratch
    __shared__ float sM[256];        // M = lw0 @ cwr0
    __shared__ float sm2[16];        // m2 = lb0 @ cwr0
    int t = threadIdx.x;
    int j = t & 15;
    {   // fused prep
        int kk = t >> 4;
        float accM = 0.f;
#pragma unroll
        for (int xx = 0; xx < 16; ++xx) accM += lw0[kk * 16 + xx] * cwr0[xx * 16 + j];
        sM[t] = accM;
        if (t < 16) {
            float a2 = 0.f;
#pragma unroll
            for (int xx = 0; xx < 16; ++xx) a2 += lb0[xx] * cwr0[xx * 16 + t];
            sm2[t] = a2;
        }
    }
    __syncthreads();
    float cwr[16], cbr[16];
#pragma unroll
    for (int k = 0; k < 16; ++k) { cwr[k] = cw0[k]; cbr[k] = cb0[k]; }

    int n = blockIdx.x * 64 + (t >> 2);   // 3125 * 64 = 200000 exactly
    int h = t & 3;
    float q[16];
#pragma unroll
    for (int k = 0; k < 16; ++k) q[k] = 0.f;
    {
        int e0 = nodeoff[n];
        int e1 = (n < N_NODES - 1) ? nodeoff[n + 1] : N_EDGES;
        int i = e0 + h;
        for (; i + 4 < e1; i += 8) {
            u32 en0 = sorted[i], en1 = sorted[i + 4];
            float2 g0 = db0[(int)(en0 & 0x3ffffu)];
            float2 g1 = db0[(int)(en1 & 0x3ffffu)];
            float a0 = ((float)(en0 >> 18) + 0.5f) * EA_DEC * g0.x;  // ea*dinv[s]
            float a1 = ((float)(en1 >> 18) + 0.5f) * EA_DEC * g1.x;
#pragma unroll
            for (int k = 0; k < 16; ++k)
                q[k] += a0 * fmaxf(g0.y * cwr[k] + cbr[k], 0.f)
                      + a1 * fmaxf(g1.y * cwr[k] + cbr[k], 0.f);
        }
        if (i < e1) {
            u32 en = sorted[i];
            float2 g = db0[(int)(en & 0x3ffffu)];
            float a = ((float)(en >> 18) + 0.5f) * EA_DEC * g.x;
#pragma unroll
            for (int k = 0; k < 16; ++k)
                q[k] += a * fmaxf(g.y * cwr[k] + cbr[k], 0.f);
        }
    }
    // combine quarters (lanes 4k..4k+3, in-wave)
#pragma unroll
    for (int k = 0; k < 16; ++k) {
        q[k] += __shfl_xor(q[k], 1);
        q[k] += __shfl_xor(q[k], 2);
    }
    float dn = 0.f, cval = 0.f;
    {
        float2 self = db0[n];
        dn = self.x;
        float ds = dn * dn;
#pragma unroll
        for (int k = 0; k < 16; ++k)
            q[k] = dn * q[k] + ds * fmaxf(self.y * cwr[k] + cbr[k], 0.f);
        cval = s1v[n];
    }
    if (h == 0) {
        float* row = sq + (t >> 2) * 20;
#pragma unroll
        for (int k = 0; k < 16; k += 4)
            *(float4*)(row + k) = make_float4(q[k], q[k + 1], q[k + 2], q[k + 3]);
        row[16] = cval;
        row[17] = dn;
    }
    __syncthreads();
    // epilogue weights loaded post edge phase (lower edge-phase VGPR)
    float Mc[16], W1c[16];
#pragma unroll
    for (int k = 0; k < 16; ++k) { Mc[k] = sM[k * 16 + j]; W1c[k] = lw1[k * 16 + j]; }
    float m2j = sm2[j], cb1j = cb1[j], lb1j = lb1[j];
    int g = t >> 4;
    float* ar = sa2 + g * 16;
    for (int it = 0; it < 4; ++it) {
        int nl = g * 4 + it;
        const float* r = sq + nl * 20;
        float4 q0 = *(const float4*)(r);
        float4 q1 = *(const float4*)(r + 4);
        float4 q2 = *(const float4*)(r + 8);
        float4 q3 = *(const float4*)(r + 12);
        float c2 = r[16], dn2 = r[17];
        float v2 = c2 * m2j + cb1j;
        v2 += q0.x * Mc[0] + q0.y * Mc[1] + q0.z * Mc[2] + q0.w * Mc[3];
        v2 += q1.x * Mc[4] + q1.y * Mc[5] + q1.z * Mc[6] + q1.w * Mc[7];
        v2 += q2.x * Mc[8] + q2.y * Mc[9] + q2.z * Mc[10] + q2.w * Mc[11];
        v2 += q3.x * Mc[12] + q3.y * Mc[13] + q3.z * Mc[14] + q3.w * Mc[15];
        ar[j] = fmaxf(v2, 0.f);          // wave-local
        float o = lb1j;
#pragma unroll
        for (int k = 0; k < 16; ++k) o += ar[k] * W1c[k];
        int n2 = blockIdx.x * 64 + nl;
        h2hat[(size_t)n2 * 16 + j] = (f16)(dn2 * o);
    }
}

// layer 2: fp16 h2hat (R13) + u32 edges (R14/R16). R17: gather window deepened
// unroll-8 -> unroll-16 — one batch covers a typical node's whole edge list,
// doubling gathers in flight per thread (agg2 shifted latency-bound after the
// fetch halvings: VALUBusy 22->34%, FETCH 121 MB). Live regs ~56-60 < the
// 64-VGPR cap for 256-thr/8-wave occupancy. 64B-aligned bases preserved.
__global__ __launch_bounds__(256) void agg2_kernel(const u32* __restrict__ sorted,
                                                   const int* __restrict__ nodeoff,
                                                   const f16* __restrict__ h2hat,
                                                   const float* __restrict__ dinv,
                                                   const float* __restrict__ cwr1,
                                                   const float* __restrict__ cb2,
                                                   const float* __restrict__ lw2,
                                                   const float* __restrict__ lb2,
                                                   float* __restrict__ h3) {
    __shared__ float sz[256];   // per (group, j) — wave-local roundtrip
    int t = threadIdx.x, j = t & 15, g = t >> 4;
    float W1c[16], W2c[16];
#pragma unroll
    for (int k = 0; k < 16; ++k) { W1c[k] = cwr1[k * 16 + j]; W2c[k] = lw2[k * 16 + j]; }
    float cb2j = cb2[j], lb2j = lb2[j];
    const float* zr = sz + g * 16;
    int nbase = blockIdx.x * 64 + g * 4;     // 3125 * 64 = 200000 exactly
#pragma unroll
    for (int it = 0; it < 4; ++it) {
        int n = nbase + it;
        int e0 = nodeoff[n];
        int e1 = (n < N_NODES - 1) ? nodeoff[n + 1] : N_EDGES;
        float q = 0.f;
        int i = e0;
        for (; i + 16 <= e1; i += 16) {
            u32 en0 = sorted[i],      en1 = sorted[i + 1],  en2 = sorted[i + 2],  en3 = sorted[i + 3];
            u32 en4 = sorted[i + 4],  en5 = sorted[i + 5],  en6 = sorted[i + 6],  en7 = sorted[i + 7];
            u32 en8 = sorted[i + 8],  en9 = sorted[i + 9],  enA = sorted[i + 10], enB = sorted[i + 11];
            u32 enC = sorted[i + 12], enD = sorted[i + 13], enE = sorted[i + 14], enF = sorted[i + 15];
            float g0 = (float)h2hat[(size_t)(en0 & 0x3ffffu) * 16 + j];
            float g1 = (float)h2hat[(size_t)(en1 & 0x3ffffu) * 16 + j];
            float g2 = (float)h2hat[(size_t)(en2 & 0x3ffffu) * 16 + j];
            float g3 = (float)h2hat[(size_t)(en3 & 0x3ffffu) * 16 + j];
            float g4 = (float)h2hat[(size_t)(en4 & 0x3ffffu) * 16 + j];
            float g5 = (float)h2hat[(size_t)(en5 & 0x3ffffu) * 16 + j];
            float g6 = (float)h2hat[(size_t)(en6 & 0x3ffffu) * 16 + j];
            float g7 = (float)h2hat[(size_t)(en7 & 0x3ffffu) * 16 + j];
            float g8 = (float)h2hat[(size_t)(en8 & 0x3ffffu) * 16 + j];
            float g9 = (float)h2hat[(size_t)(en9 & 0x3ffffu) * 16 + j];
            float gA = (float)h2hat[(size_t)(enA & 0x3ffffu) * 16 + j];
            float gB = (float)h2hat[(size_t)(enB & 0x3ffffu) * 16 + j];
            float gC = (float)h2hat[(size_t)(enC & 0x3ffffu) * 16 + j];
            float gD = (float)h2hat[(size_t)(enD & 0x3ffffu) * 16 + j];
            float gE = (float)h2hat[(size_t)(enE & 0x3ffffu) * 16 + j];
            float gF = (float)h2hat[(size_t)(enF & 0x3ffffu) * 16 + j];
            q += (((float)(en0 >> 18) + 0.5f) * EA_DEC) * g0
               + (((float)(en1 >> 18) + 0.5f) * EA_DEC) * g1
               + (((float)(en2 >> 18) + 0.5f) * EA_DEC) * g2
               + (((float)(en3 >> 18) + 0.5f) * EA_DEC) * g3
               + (((float)(en4 >> 18) + 0.5f) * EA_DEC) * g4
               + (((float)(en5 >> 18) + 0.5f) * EA_DEC) * g5
               + (((float)(en6 >> 18) + 0.5f) * EA_DEC) * g6
               + (((float)(en7 >> 18) + 0.5f) * EA_DEC) * g7
               + (((float)(en8 >> 18) + 0.5f) * EA_DEC) * g8
               + (((float)(en9 >> 18) + 0.5f) * EA_DEC) * g9
               + (((float)(enA >> 18) + 0.5f) * EA_DEC) * gA
               + (((float)(enB >> 18) + 0.5f) * EA_DEC) * gB
               + (((float)(enC >> 18) + 0.5f) * EA_DEC) * gC
               + (((float)(enD >> 18) + 0.5f) * EA_DEC) * gD
               + (((float)(enE >> 18) + 0.5f) * EA_DEC) * gE
               + (((float)(enF >> 18) + 0.5f) * EA_DEC) * gF;
        }
        for (; i + 8 <= e1; i += 8) {
            u32 en0 = sorted[i],     en1 = sorted[i + 1], en2 = sorted[i + 2], en3 = sorted[i + 3];
            u32 en4 = sorted[i + 4], en5 = sorted[i + 5], en6 = sorted[i + 6], en7 = sorted[i + 7];
            float g0 = (float)h2hat[(size_t)(en0 & 0x3ffffu) * 16 + j];
            float g1 = (float)h2hat[(size_t)(en1 & 0x3ffffu) * 16 + j];
            float g2 = (float)h2hat[(size_t)(en2 & 0x3ffffu) * 16 + j];
            float g3 = (float)h2hat[(size_t)(en3 & 0x3ffffu) * 16 + j];
            float g4 = (float)h2hat[(size_t)(en4 & 0x3ffffu) * 16 + j];
            float g5 = (float)h2hat[(size_t)(en5 & 0x3ffffu) * 16 + j];
            float g6 = (float)h2hat[(size_t)(en6 & 0x3ffffu) * 16 + j];
            float g7 = (float)h2hat[(size_t)(en7 & 0x3ffffu) * 16 + j];
            q += (((float)(en0 >> 18) + 0.5f) * EA_DEC) * g0
               + (((float)(en1 >> 18) + 0.5f) * EA_DEC) * g1
               + (((float)(en2 >> 18) + 0.5f) * EA_DEC) * g2
               + (((float)(en3 >> 18) + 0.5f) * EA_DEC) * g3
               + (((float)(en4 >> 18) + 0.5f) * EA_DEC) * g4
               + (((float)(en5 >> 18) + 0.5f) * EA_DEC) * g5
               + (((float)(en6 >> 18) + 0.5f) * EA_DEC) * g6
               + (((float)(en7 >> 18) + 0.5f) * EA_DEC) * g7;
        }
        for (; i < e1; ++i) {
            u32 en = sorted[i];
            q += (((float)(en >> 18) + 0.5f) * EA_DEC)
               * (float)h2hat[(size_t)(en & 0x3ffffu) * 16 + j];
        }
        float dn = dinv[n];
        float z = dn * (q + (float)h2hat[(size_t)n * 16 + j]);   // + dn^2 * h2[n]
        sz[t] = z;                                        // wave-local
        float v = cb2j;
#pragma unroll
        for (int k = 0; k < 16; ++k) v += zr[k] * W1c[k];
        float a = fmaxf(v, 0.f);
        sz[t] = a;                                        // wave-local overwrite
        float o = lb2j;
#pragma unroll
        for (int k = 0; k < 16; ++k) o += zr[k] * W2c[k];
        h3[(size_t)n * 16 + j] = o;
    }
}

// fused attention-pool + final MLP: one 64-thread wave per graph.
__global__ __launch_bounds__(64) void poolfinal_kernel(const float* __restrict__ h3,
                                                       const int* __restrict__ batch,
                                                       const float* __restrict__ w1,
                                                       const float* __restrict__ b1,
                                                       const float* __restrict__ w2,
                                                       const float* __restrict__ b2,
                                                       const float* __restrict__ w3,
                                                       const float* __restrict__ b3,
                                                       float* __restrict__ out) {
    int g = blockIdx.x;
    int t = threadIdx.x;
    int j = t & 15, sg = t >> 4;
    __shared__ int range[2];
    if (t < 2) {
        int target = g + t;          // lower_bound(batch, g) / lower_bound(batch, g+1)
        int lo = 0, hi = N_NODES;
        while (lo < hi) {
            int mid = (lo + hi) >> 1;
            if (batch[mid] < target) lo = mid + 1; else hi = mid;
        }
        range[t] = lo;
    }
    __syncthreads();
    int n0 = range[0], n1 = range[1];
    float accn = 0.f, accd = 0.f;
    for (int n = n0 + sg; n < n1; n += 4) {
        float v = h3[(size_t)n * 16 + j];
        float e = __expf(ALPHA_ * v);
        accn += v * e;
        accd += e;
    }
    accn += __shfl_xor(accn, 16);
    accd += __shfl_xor(accd, 16);
    accn += __shfl_xor(accn, 32);
    accd += __shfl_xor(accd, 32);
    __shared__ float sp[16], st1[16], st2[16];
    if (t < 16) sp[j] = (accd > 0.f) ? accn / accd : 0.f;
    __syncthreads();
    if (t < 16) {
        float acc = b1[j];
#pragma unroll
        for (int k = 0; k < 16; ++k) acc += sp[k] * w1[k * 16 + j];
        st1[j] = fmaxf(acc, 0.f);
    }
    __syncthreads();
    if (t < 16) {
        float acc = b2[j];
#pragma unroll
        for (int k = 0; k < 16; ++k) acc += st1[k] * w2[k * 16 + j];
        st2[j] = fmaxf(acc, 0.f);
    }
    __syncthreads();
    if (t == 0) {
        float o = b3[0];
#pragma unroll
        for (int k = 0; k < 16; ++k) o += st2[k] * w3[k];
        out[g] = o;
    }
}

extern "C" void kernel_launch(void* const* d_in, const int* in_sizes, int n_in,
                              void* d_out, int out_size, void* d_ws, size_t ws_size,
                              hipStream_t stream) {
    const float* x   = (const float*)d_in[0];
    const int*   ei  = (const int*)d_in[1];
    const int*   src = ei;
    const int*   dst = ei + N_EDGES;
    const int*   batch = (const int*)d_in[2];
    const float* ea  = (const float*)d_in[3];
    const float* cw0 = (const float*)d_in[4];
    const float* cwr = (const float*)d_in[5];
    const float* cb  = (const float*)d_in[6];
    const float* lw  = (const float*)d_in[7];
    const float* lb  = (const float*)d_in[8];
    const float* w1  = (const float*)d_in[9];
    const float* b1  = (const float*)d_in[10];
    const float* w2  = (const float*)d_in[11];
    const float* b2  = (const float*)d_in[12];
    const float* w3  = (const float*)d_in[13];
    const float* b3  = (const float*)d_in[14];
    float* out = (float*)d_out;

    // workspace layout (4-byte units) — ALL segment bases multiple of 64 floats
    // (256 B) so row structures (h2hat fp16 32B rows / h3 fp32 64B rows) never
    // straddle cache lines.
    float* ws      = (float*)d_ws;
    float* dinv    = ws;                                   // 200000  (0)
    float* s1v     = ws + 200000;                          // 200000
    float2* db0    = (float2*)(ws + 400000);               // 400000 floats
    int*   nodeoff = (int*)(ws + 800000);                  // 200010 -> pad 200064
    int*   gcursor = (int*)(ws + 1000064);                 // 392 -> pad 448
    float2* dx     = (float2*)(ws + 1000512);              // 400000 floats
    u64* bucketedP = (u64*)(ws + 1400512);                 // 391*9216 u64 = 7206912 floats
    u32* sorted    = (u32*)(ws + 8607424);                 // 3.2M u32 = 3200000 floats
    f16* h2hat     = (f16*)(ws + 1400512);                 // alias bucketedP; 3.2M halves = 1.6M floats
    float* h3      = (float*)(ws + 3000512);               // alias (within bucketedP region), 64B-aligned

    hipMemsetAsync(gcursor, 0, (size_t)448 * sizeof(int), stream);

    // single-pass bucketing (global atomic reservation, LDS-sorted coalesced runs)
    bucket_kernel<<<NBLKA, 1024, 0, stream>>>(src, dst, ea, gcursor, bucketedP);
    // in-bucket counting sort: self-computed compact base (scanB fused in),
    // two-pass L2-hot read + fused degree + LDS-staged u32 output
    sortd_kernel<<<NBUCK, 1024, 0, stream>>>(bucketedP, gcursor, x, sorted, nodeoff, dinv, dx);

    // layer 0 (4 threads/node) -> db0={dinv,base0}, s1
    agg0_kernel<<<3125, 256, 0, stream>>>(sorted, nodeoff, dx, db0, s1v);
    // layer 1 (4 threads/node + fused prep + 2-stage epilogue) -> h2hat (fp16)
    agg1_kernel<<<3125, 256, 0, stream>>>(sorted, nodeoff, db0, s1v,
                                          cw0, cb, lw, lb,
                                          cwr, cb + 16, lw + 256, lb + 16, h2hat);
    // layer 2 (unroll-16 gathers, fp16 h2hat reads, u32 edges) -> h3
    agg2_kernel<<<3125, 256, 0, stream>>>(sorted, nodeoff, h2hat, dinv,
                                          cwr + 256, cb + 32, lw + 512, lb + 32, h3);

    // fused attention pooling + final MLP (one wave per graph)
    poolfinal_kernel<<<N_GRAPHS, 64, 0, stream>>>(h3, batch, w1, b1, w2, b2, w3, b3, out);
}

// Round 18
// 274.599 us; speedup vs baseline: 1.0735x; 1.0735x over previous
//
#include <hip/hip_runtime.h>

#define N_NODES 200000
#define N_EDGES 3200000
#define N_GRAPHS 1024
#define HD 16
#define ALPHA_ 0.2f

#define BNODES 512                 // nodes per bucket (dst >> 9)
#define NBUCK 391                  // ceil(N_NODES/512)
#define CHUNKA 8192                // edges per bucket-pass block (1024 thr x 2 x int4)
#define NBLKA 391                  // ceil(N_EDGES/8192)
#define CAP 9216                   // padded bucket capacity (mean 8192, sigma~90, +11 sigma)

#define EA_DEC 6.103515625e-05f    // 1/16384 — 14-bit fixed-point ea decode

typedef unsigned long long u64;
typedef unsigned int u32;
typedef _Float16 f16;

// ---------- single-pass bucketing ----------
// R9 (keeper): entries locally counting-sorted by bucket-id into a 64 KB LDS
// stage, then each ~21-entry run written with CONSECUTIVE lanes.
// R11: shfl_up wave scan (2 barriers); half-wave write-out granularity.
// bucketedP entry = (ea:f32 | dlow:9 | src:18)  (full-precision ea kept here
// because sortd's degree sums need it).
__global__ __launch_bounds__(1024) void bucket_kernel(const int* __restrict__ src,
                                                      const int* __restrict__ dst,
                                                      const float* __restrict__ ea,
                                                      int* __restrict__ gcursor,
                                                      u64* __restrict__ bucketedP) {
    __shared__ int hist[NBUCK];
    __shared__ int lstart[NBUCK];
    __shared__ int lcur[NBUCK];
    __shared__ int gbase[NBUCK];
    __shared__ int sincl[512];
    __shared__ int wsum[8];
    __shared__ u64 stage[CHUNKA];        // 64 KB; total ~72 KB -> 2 blocks/CU
    int t = threadIdx.x;
    if (t < NBUCK) hist[t] = 0;
    __syncthreads();
    int e0 = blockIdx.x * CHUNKA;
    int e1 = min(e0 + CHUNKA, N_EDGES);
    int ia = e0 + (t << 2);
    int ib = e0 + 4096 + (t << 2);
    bool va = ia < e1, vb = ib < e1;
    int4 d4a, d4b;
    if (va) {   // edges multiple of 4 -> full int4 valid; dst held in regs for pass 2
        d4a = *(const int4*)(dst + ia);
        atomicAdd(&hist[d4a.x >> 9], 1);
        atomicAdd(&hist[d4a.y >> 9], 1);
        atomicAdd(&hist[d4a.z >> 9], 1);
        atomicAdd(&hist[d4a.w >> 9], 1);
    }
    if (vb) {
        d4b = *(const int4*)(dst + ib);
        atomicAdd(&hist[d4b.x >> 9], 1);
        atomicAdd(&hist[d4b.y >> 9], 1);
        atomicAdd(&hist[d4b.z >> 9], 1);
        atomicAdd(&hist[d4b.w >> 9], 1);
    }
    __syncthreads();
    // exclusive scan over 391 bins: shfl_up wave scan + 8-wavesum fixup
    int c = (t < NBUCK) ? hist[t] : 0;
    if (t < 512) {
        int lane = t & 63;
        int incl = c;
#pragma unroll
        for (int off = 1; off < 64; off <<= 1) {
            int v = __shfl_up(incl, off);
            if (lane >= off) incl += v;
        }
        sincl[t] = incl;
        if (lane == 63) wsum[t >> 6] = incl;
    }
    __syncthreads();
    if (t == 0) {
        int run = 0;
#pragma unroll
        for (int w = 0; w < 8; ++w) { int v = wsum[w]; wsum[w] = run; run += v; }
    }
    __syncthreads();
    if (t < NBUCK) {
        int ls = sincl[t] - c + wsum[t >> 6];
        lstart[t] = ls;
        lcur[t] = ls;
        gbase[t] = (c > 0) ? (t * CAP + atomicAdd(&gcursor[t], c)) : 0;
    }
    __syncthreads();
    // scatter into LDS stage, ordered by bucket
    if (va) {
        int4   s4 = *(const int4*)(src + ia);
        float4 a4 = *(const float4*)(ea + ia);
        int p0 = atomicAdd(&lcur[d4a.x >> 9], 1);
        int p1 = atomicAdd(&lcur[d4a.y >> 9], 1);
        int p2 = atomicAdd(&lcur[d4a.z >> 9], 1);
        int p3 = atomicAdd(&lcur[d4a.w >> 9], 1);
        stage[p0] = ((u64)__float_as_uint(a4.x) << 32) | (unsigned)(s4.x | ((d4a.x & 511) << 18));
        stage[p1] = ((u64)__float_as_uint(a4.y) << 32) | (unsigned)(s4.y | ((d4a.y & 511) << 18));
        stage[p2] = ((u64)__float_as_uint(a4.z) << 32) | (unsigned)(s4.z | ((d4a.z & 511) << 18));
        stage[p3] = ((u64)__float_as_uint(a4.w) << 32) | (unsigned)(s4.w | ((d4a.w & 511) << 18));
    }
    if (vb) {
        int4   s4 = *(const int4*)(src + ib);
        float4 a4 = *(const float4*)(ea + ib);
        int p0 = atomicAdd(&lcur[d4b.x >> 9], 1);
        int p1 = atomicAdd(&lcur[d4b.y >> 9], 1);
        int p2 = atomicAdd(&lcur[d4b.z >> 9], 1);
        int p3 = atomicAdd(&lcur[d4b.w >> 9], 1);
        stage[p0] = ((u64)__float_as_uint(a4.x) << 32) | (unsigned)(s4.x | ((d4b.x & 511) << 18));
        stage[p1] = ((u64)__float_as_uint(a4.y) << 32) | (unsigned)(s4.y | ((d4b.y & 511) << 18));
        stage[p2] = ((u64)__float_as_uint(a4.z) << 32) | (unsigned)(s4.z | ((d4b.z & 511) << 18));
        stage[p3] = ((u64)__float_as_uint(a4.w) << 32) | (unsigned)(s4.w | ((d4b.w & 511) << 18));
    }
    __syncthreads();
    // write-out: half-wave (32 lanes) per bucket -> two runs per wave store inst
    int hw = t >> 5, lane = t & 31;
    for (int u = hw; u < NBUCK; u += 32) {
        int c2 = hist[u];
        int ls = lstart[u];
        int gb = gbase[u];
        for (int k = lane; k < c2; k += 32)
            bucketedP[gb + k] = stage[ls + k];
    }
}

// in-bucket counting sort by dlow (9b) + fused degree (LDS f32 atomics).
// R12 (keeper): scanB fused — per-block compact base via shfl reduction.
// R14: u32 sorted entries = (ea_q14:14 | src:18).
// R16 (keeper): NO register array — bucketedP read twice (second pass L2-hot);
// live state in scatter loop = one u64 -> no spill at the 64-VGPR/1024-thr cap.
__global__ __launch_bounds__(1024) void sortd_kernel(const u64* __restrict__ bucketedP,
                                                     const int* __restrict__ gcursor,
                                                     const float* __restrict__ x,
                                                     u32* __restrict__ sorted,
                                                     int* __restrict__ nodeoff,
                                                     float* __restrict__ dinv,
                                                     float2* __restrict__ dx) {
    __shared__ int hist[512];
    __shared__ int cur[512];
    __shared__ float fdeg[512];
    __shared__ int sincl[512];
    __shared__ int wsum[8];
    __shared__ int wred[16];
    __shared__ int sb0;
    __shared__ u32 stage[CAP];          // 36 KB; total ~45 KB
    int u = blockIdx.x, t = threadIdx.x;
    if (t < 512) { hist[t] = 0; fdeg[t] = 0.f; }
    // compact base: b0 = sum of gcursor[0..u-1]  (16 waves cover 1024 slots)
    {
        int lane = t & 63, wv = t >> 6;
        int v = (t < u) ? gcursor[t] : 0;    // u <= 391 < 1024
#pragma unroll
        for (int off = 1; off < 64; off <<= 1) v += __shfl_xor(v, off);
        if (lane == 0) wred[wv] = v;
    }
    __syncthreads();
    if (t == 0) {
        int b = 0;
#pragma unroll
        for (int w = 0; w < 16; ++w) b += wred[w];
        sb0 = b;
    }
    int m = gcursor[u];                  // bucket count (<= CAP)
    const u64* bp = bucketedP + (size_t)u * CAP;
    // pass 1: hist + weighted degree (full-precision ea)
    for (int i = t; i < m; i += 1024) {
        u64 ent = bp[i];
        int dl = (int)((ent >> 18) & 511u);
        atomicAdd(&hist[dl], 1);
        atomicAdd(&fdeg[dl], __uint_as_float((unsigned)(ent >> 32)));
    }
    __syncthreads();
    int b0 = sb0;
    // exclusive scan over 512 bins: shfl_up wave scan + 8-wavesum fixup
    int c = (t < 512) ? hist[t] : 0;
    if (t < 512) {
        int lane = t & 63;
        int incl = c;
#pragma unroll
        for (int off = 1; off < 64; off <<= 1) {
            int v = __shfl_up(incl, off);
            if (lane >= off) incl += v;
        }
        sincl[t] = incl;
        if (lane == 63) wsum[t >> 6] = incl;
    }
    __syncthreads();
    if (t == 0) {
        int run = 0;
#pragma unroll
        for (int w = 0; w < 8; ++w) { int v = wsum[w]; wsum[w] = run; run += v; }
    }
    __syncthreads();
    if (t < 512) {
        int excl = sincl[t] - c + wsum[t >> 6];   // bucket-local exclusive
        cur[t] = excl;
        int n = u * BNODES + t;
        if (n < N_NODES) {
            nodeoff[n] = b0 + excl;
            float dn = rsqrtf(fdeg[t] + 1.0f);
            dinv[n] = dn;
            dx[n] = make_float2(dn, dn * x[n]);
        }
    }
    __syncthreads();
    // pass 2: re-read (L2-hot), quantize ea -> 14-bit, scatter u32 into LDS
    for (int i = t; i < m; i += 1024) {
        u64 ent = bp[i];
        int pos = atomicAdd(&cur[(int)((ent >> 18) & 511u)], 1);
        float eaf = __uint_as_float((unsigned)(ent >> 32));
        unsigned q = (unsigned)(eaf * 16384.0f);
        if (q > 16383u) q = 16383u;
        stage[pos] = (q << 18) | (u32)(ent & 0x3ffffu);
    }
    __syncthreads();
    for (int i = t; i < m; i += 1024)
        sorted[b0 + i] = stage[i];       // coalesced 4B stores
}

// layer 0: 4 threads/node (stride-4, 2 gathers in flight), 2-level shfl combine
__global__ __launch_bounds__(256) void agg0_kernel(const u32* __restrict__ sorted,
                                                   const int* __restrict__ nodeoff,
                                                   const float2* __restrict__ dx,
                                                   float2* __restrict__ db0,
                                                   float* __restrict__ s1v) {
    int t = threadIdx.x;
    int n = blockIdx.x * 64 + (t >> 2);   // 3125 * 64 = 200000 exactly
    int h = t & 3;
    float acc = 0.f, wsum = 0.f;
    {
        int e0 = nodeoff[n];
        int e1 = (n < N_NODES - 1) ? nodeoff[n + 1] : N_EDGES;
        int i = e0 + h;
        for (; i + 4 < e1; i += 8) {
            u32 en0 = sorted[i], en1 = sorted[i + 4];
            float2 g0 = dx[(int)(en0 & 0x3ffffu)];
            float2 g1 = dx[(int)(en1 & 0x3ffffu)];
            float a0 = ((float)(en0 >> 18) + 0.5f) * EA_DEC;
            float a1 = ((float)(en1 >> 18) + 0.5f) * EA_DEC;
            acc  += a0 * g0.y + a1 * g1.y;
            wsum += a0 * g0.x + a1 * g1.x;
        }
        if (i < e1) {
            u32 en = sorted[i];
            float2 g = dx[(int)(en & 0x3ffffu)];
            float a = ((float)(en >> 18) + 0.5f) * EA_DEC;
            acc += a * g.y;
            wsum += a * g.x;
        }
    }
    acc += __shfl_xor(acc, 1);
    wsum += __shfl_xor(wsum, 1);
    acc += __shfl_xor(acc, 2);
    wsum += __shfl_xor(wsum, 2);
    if (h == 0) {
        float2 d2 = dx[n];
        float dn = d2.x;
        float base0 = dn * acc + dn * d2.y;     // + dn^2 * x[n]
        db0[n] = make_float2(dn, base0);
        s1v[n] = dn * wsum + dn * dn;
    }
}

// layer 1: 4 threads/node edge phase (mirrors agg0), 2-level shfl combine, then
// 16-lane epilogue. fp16 h2hat out (R13 keeper; fp32 accumulation).
__global__ __launch_bounds__(256) void agg1_kernel(const u32* __restrict__ sorted,
                                                   const int* __restrict__ nodeoff,
                                                   const float2* __restrict__ db0,
                                                   const float* __restrict__ s1v,
                                                   const float* __restrict__ cw0,
                                                   const float* __restrict__ cb0,
                                                   const float* __restrict__ lw0,
                                                   const float* __restrict__ lb0,
                                                   const float* __restrict__ cwr0,
                                                   const float* __restrict__ cb1,
                                                   const float* __restrict__ lw1,
                                                   const float* __restrict__ lb1,
                                                   f16* __restrict__ h2hat) {
    __shared__ float sq[64 * 20];    // per node: q[16], c, dn, pad2  (5 KB)
    __shared__ float sa2[256];       // wave-local relu scratch
    __shared__ float sM[256];        // M = lw0 @ cwr0
    __shared__ float sm2[16];        // m2 = lb0 @ cwr0
    int t = threadIdx.x;
    int j = t & 15;
    {   // fused prep
        int kk = t >> 4;
        float accM = 0.f;
#pragma unroll
        for (int xx = 0; xx < 16; ++xx) accM += lw0[kk * 16 + xx] * cwr0[xx * 16 + j];
        sM[t] = accM;
        if (t < 16) {
            float a2 = 0.f;
#pragma unroll
            for (int xx = 0; xx < 16; ++xx) a2 += lb0[xx] * cwr0[xx * 16 + t];
            sm2[t] = a2;
        }
    }
    __syncthreads();
    float cwr[16], cbr[16];
#pragma unroll
    for (int k = 0; k < 16; ++k) { cwr[k] = cw0[k]; cbr[k] = cb0[k]; }

    int n = blockIdx.x * 64 + (t >> 2);   // 3125 * 64 = 200000 exactly
    int h = t & 3;
    float q[16];
#pragma unroll
    for (int k = 0; k < 16; ++k) q[k] = 0.f;
    {
        int e0 = nodeoff[n];
        int e1 = (n < N_NODES - 1) ? nodeoff[n + 1] : N_EDGES;
        int i = e0 + h;
        for (; i + 4 < e1; i += 8) {
            u32 en0 = sorted[i], en1 = sorted[i + 4];
            float2 g0 = db0[(int)(en0 & 0x3ffffu)];
            float2 g1 = db0[(int)(en1 & 0x3ffffu)];
            float a0 = ((float)(en0 >> 18) + 0.5f) * EA_DEC * g0.x;  // ea*dinv[s]
            float a1 = ((float)(en1 >> 18) + 0.5f) * EA_DEC * g1.x;
#pragma unroll
            for (int k = 0; k < 16; ++k)
                q[k] += a0 * fmaxf(g0.y * cwr[k] + cbr[k], 0.f)
                      + a1 * fmaxf(g1.y * cwr[k] + cbr[k], 0.f);
        }
        if (i < e1) {
            u32 en = sorted[i];
            float2 g = db0[(int)(en & 0x3ffffu)];
            float a = ((float)(en >> 18) + 0.5f) * EA_DEC * g.x;
#pragma unroll
            for (int k = 0; k < 16; ++k)
                q[k] += a * fmaxf(g.y * cwr[k] + cbr[k], 0.f);
        }
    }
    // combine quarters (lanes 4k..4k+3, in-wave)
#pragma unroll
    for (int k = 0; k < 16; ++k) {
        q[k] += __shfl_xor(q[k], 1);
        q[k] += __shfl_xor(q[k], 2);
    }
    float dn = 0.f, cval = 0.f;
    {
        float2 self = db0[n];
        dn = self.x;
        float ds = dn * dn;
#pragma unroll
        for (int k = 0; k < 16; ++k)
            q[k] = dn * q[k] + ds * fmaxf(self.y * cwr[k] + cbr[k], 0.f);
        cval = s1v[n];
    }
    if (h == 0) {
        float* row = sq + (t >> 2) * 20;
#pragma unroll
        for (int k = 0; k < 16; k += 4)
            *(float4*)(row + k) = make_float4(q[k], q[k + 1], q[k + 2], q[k + 3]);
        row[16] = cval;
        row[17] = dn;
    }
    __syncthreads();
    // epilogue weights loaded post edge phase (lower edge-phase VGPR)
    float Mc[16], W1c[16];
#pragma unroll
    for (int k = 0; k < 16; ++k) { Mc[k] = sM[k * 16 + j]; W1c[k] = lw1[k * 16 + j]; }
    float m2j = sm2[j], cb1j = cb1[j], lb1j = lb1[j];
    int g = t >> 4;
    float* ar = sa2 + g * 16;
    for (int it = 0; it < 4; ++it) {
        int nl = g * 4 + it;
        const float* r = sq + nl * 20;
        float4 q0 = *(const float4*)(r);
        float4 q1 = *(const float4*)(r + 4);
        float4 q2 = *(const float4*)(r + 8);
        float4 q3 = *(const float4*)(r + 12);
        float c2 = r[16], dn2 = r[17];
        float v2 = c2 * m2j + cb1j;
        v2 += q0.x * Mc[0] + q0.y * Mc[1] + q0.z * Mc[2] + q0.w * Mc[3];
        v2 += q1.x * Mc[4] + q1.y * Mc[5] + q1.z * Mc[6] + q1.w * Mc[7];
        v2 += q2.x * Mc[8] + q2.y * Mc[9] + q2.z * Mc[10] + q2.w * Mc[11];
        v2 += q3.x * Mc[12] + q3.y * Mc[13] + q3.z * Mc[14] + q3.w * Mc[15];
        ar[j] = fmaxf(v2, 0.f);          // wave-local
        float o = lb1j;
#pragma unroll
        for (int k = 0; k < 16; ++k) o += ar[k] * W1c[k];
        int n2 = blockIdx.x * 64 + nl;
        h2hat[(size_t)n2 * 16 + j] = (f16)(dn2 * o);
    }
}

// layer 2: fp16 h2hat (R13) + u32 edges (R14/R16), unroll-8 — FINAL form.
// The 8-deep gather window at 36 VGPR / ~59% occupancy is the empirical
// optimum, confirmed from both sides: R17's unroll-16 (48 VGPR, occ 40%)
// regressed to 79 us; R2-fusion (48 VGPR) regressed to 94; R4 misalignment
// regressed via line-straddle. Do not deepen, fuse into, or misalign this.
__global__ __launch_bounds__(256) void agg2_kernel(const u32* __restrict__ sorted,
                                                   const int* __restrict__ nodeoff,
                                                   const f16* __restrict__ h2hat,
                                                   const float* __restrict__ dinv,
                                                   const float* __restrict__ cwr1,
                                                   const float* __restrict__ cb2,
                                                   const float* __restrict__ lw2,
                                                   const float* __restrict__ lb2,
                                                   float* __restrict__ h3) {
    __shared__ float sz[256];   // per (group, j) — wave-local roundtrip
    int t = threadIdx.x, j = t & 15, g = t >> 4;
    float W1c[16], W2c[16];
#pragma unroll
    for (int k = 0; k < 16; ++k) { W1c[k] = cwr1[k * 16 + j]; W2c[k] = lw2[k * 16 + j]; }
    float cb2j = cb2[j], lb2j = lb2[j];
    const float* zr = sz + g * 16;
    int nbase = blockIdx.x * 64 + g * 4;     // 3125 * 64 = 200000 exactly
#pragma unroll
    for (int it = 0; it < 4; ++it) {
        int n = nbase + it;
        int e0 = nodeoff[n];
        int e1 = (n < N_NODES - 1) ? nodeoff[n + 1] : N_EDGES;
        float q = 0.f;
        int i = e0;
        for (; i + 8 <= e1; i += 8) {
            u32 en0 = sorted[i],     en1 = sorted[i + 1], en2 = sorted[i + 2], en3 = sorted[i + 3];
            u32 en4 = sorted[i + 4], en5 = sorted[i + 5], en6 = sorted[i + 6], en7 = sorted[i + 7];
            float g0 = (float)h2hat[(size_t)(en0 & 0x3ffffu) * 16 + j];
            float g1 = (float)h2hat[(size_t)(en1 & 0x3ffffu) * 16 + j];
            float g2 = (float)h2hat[(size_t)(en2 & 0x3ffffu) * 16 + j];
            float g3 = (float)h2hat[(size_t)(en3 & 0x3ffffu) * 16 + j];
            float g4 = (float)h2hat[(size_t)(en4 & 0x3ffffu) * 16 + j];
            float g5 = (float)h2hat[(size_t)(en5 & 0x3ffffu) * 16 + j];
            float g6 = (float)h2hat[(size_t)(en6 & 0x3ffffu) * 16 + j];
            float g7 = (float)h2hat[(size_t)(en7 & 0x3ffffu) * 16 + j];
            q += (((float)(en0 >> 18) + 0.5f) * EA_DEC) * g0
               + (((float)(en1 >> 18) + 0.5f) * EA_DEC) * g1
               + (((float)(en2 >> 18) + 0.5f) * EA_DEC) * g2
               + (((float)(en3 >> 18) + 0.5f) * EA_DEC) * g3
               + (((float)(en4 >> 18) + 0.5f) * EA_DEC) * g4
               + (((float)(en5 >> 18) + 0.5f) * EA_DEC) * g5
               + (((float)(en6 >> 18) + 0.5f) * EA_DEC) * g6
               + (((float)(en7 >> 18) + 0.5f) * EA_DEC) * g7;
        }
        for (; i < e1; ++i) {
            u32 en = sorted[i];
            q += (((float)(en >> 18) + 0.5f) * EA_DEC)
               * (float)h2hat[(size_t)(en & 0x3ffffu) * 16 + j];
        }
        float dn = dinv[n];
        float z = dn * (q + (float)h2hat[(size_t)n * 16 + j]);   // + dn^2 * h2[n]
        sz[t] = z;                                        // wave-local
        float v = cb2j;
#pragma unroll
        for (int k = 0; k < 16; ++k) v += zr[k] * W1c[k];
        float a = fmaxf(v, 0.f);
        sz[t] = a;                                        // wave-local overwrite
        float o = lb2j;
#pragma unroll
        for (int k = 0; k < 16; ++k) o += zr[k] * W2c[k];
        h3[(size_t)n * 16 + j] = o;
    }
}

// fused attention-pool + final MLP: one 64-thread wave per graph.
__global__ __launch_bounds__(64) void poolfinal_kernel(const float* __restrict__ h3,
                                                       const int* __restrict__ batch,
                                                       const float* __restrict__ w1,
                                                       const float* __restrict__ b1,
                                                       const float* __restrict__ w2,
                                                       const float* __restrict__ b2,
                                                       const float* __restrict__ w3,
                                                       const float* __restrict__ b3,
                                                       float* __restrict__ out) {
    int g = blockIdx.x;
    int t = threadIdx.x;
    int j = t & 15, sg = t >> 4;
    __shared__ int range[2];
    if (t < 2) {
        int target = g + t;          // lower_bound(batch, g) / lower_bound(batch, g+1)
        int lo = 0, hi = N_NODES;
        while (lo < hi) {
            int mid = (lo + hi) >> 1;
            if (batch[mid] < target) lo = mid + 1; else hi = mid;
        }
        range[t] = lo;
    }
    __syncthreads();
    int n0 = range[0], n1 = range[1];
    float accn = 0.f, accd = 0.f;
    for (int n = n0 + sg; n < n1; n += 4) {
        float v = h3[(size_t)n * 16 + j];
        float e = __expf(ALPHA_ * v);
        accn += v * e;
        accd += e;
    }
    accn += __shfl_xor(accn, 16);
    accd += __shfl_xor(accd, 16);
    accn += __shfl_xor(accn, 32);
    accd += __shfl_xor(accd, 32);
    __shared__ float sp[16], st1[16], st2[16];
    if (t < 16) sp[j] = (accd > 0.f) ? accn / accd : 0.f;
    __syncthreads();
    if (t < 16) {
        float acc = b1[j];
#pragma unroll
        for (int k = 0; k < 16; ++k) acc += sp[k] * w1[k * 16 + j];
        st1[j] = fmaxf(acc, 0.f);
    }
    __syncthreads();
    if (t < 16) {
        float acc = b2[j];
#pragma unroll
        for (int k = 0; k < 16; ++k) acc += st1[k] * w2[k * 16 + j];
        st2[j] = fmaxf(acc, 0.f);
    }
    __syncthreads();
    if (t == 0) {
        float o = b3[0];
#pragma unroll
        for (int k = 0; k < 16; ++k) o += st2[k] * w3[k];
        out[g] = o;
    }
}

extern "C" void kernel_launch(void* const* d_in, const int* in_sizes, int n_in,
                              void* d_out, int out_size, void* d_ws, size_t ws_size,
                              hipStream_t stream) {
    const float* x   = (const float*)d_in[0];
    const int*   ei  = (const int*)d_in[1];
    const int*   src = ei;
    const int*   dst = ei + N_EDGES;
    const int*   batch = (const int*)d_in[2];
    const float* ea  = (const float*)d_in[3];
    const float* cw0 = (const float*)d_in[4];
    const float* cwr = (const float*)d_in[5];
    const float* cb  = (const float*)d_in[6];
    const float* lw  = (const float*)d_in[7];
    const float* lb  = (const float*)d_in[8];
    const float* w1  = (const float*)d_in[9];
    const float* b1  = (const float*)d_in[10];
    const float* w2  = (const float*)d_in[11];
    const float* b2  = (const float*)d_in[12];
    const float* w3  = (const float*)d_in[13];
    const float* b3  = (const float*)d_in[14];
    float* out = (float*)d_out;

    // workspace layout (4-byte units) — ALL segment bases multiple of 64 floats
    // (256 B) so row structures (h2hat fp16 32B rows / h3 fp32 64B rows) never
    // straddle cache lines.
    float* ws      = (float*)d_ws;
    float* dinv    = ws;                                   // 200000  (0)
    float* s1v     = ws + 200000;                          // 200000
    float2* db0    = (float2*)(ws + 400000);               // 400000 floats
    int*   nodeoff = (int*)(ws + 800000);                  // 200010 -> pad 200064
    int*   gcursor = (int*)(ws + 1000064);                 // 392 -> pad 448
    float2* dx     = (float2*)(ws + 1000512);              // 400000 floats
    u64* bucketedP = (u64*)(ws + 1400512);                 // 391*9216 u64 = 7206912 floats
    u32* sorted    = (u32*)(ws + 8607424);                 // 3.2M u32 = 3200000 floats
    f16* h2hat     = (f16*)(ws + 1400512);                 // alias bucketedP; 3.2M halves = 1.6M floats
    float* h3      = (float*)(ws + 3000512);               // alias (within bucketedP region), 64B-aligned

    hipMemsetAsync(gcursor, 0, (size_t)448 * sizeof(int), stream);

    // single-pass bucketing (global atomic reservation, LDS-sorted coalesced runs)
    bucket_kernel<<<NBLKA, 1024, 0, stream>>>(src, dst, ea, gcursor, bucketedP);
    // in-bucket counting sort: self-computed compact base (scanB fused in),
    // two-pass L2-hot read + fused degree + LDS-staged u32 output
    sortd_kernel<<<NBUCK, 1024, 0, stream>>>(bucketedP, gcursor, x, sorted, nodeoff, dinv, dx);

    // layer 0 (4 threads/node) -> db0={dinv,base0}, s1
    agg0_kernel<<<3125, 256, 0, stream>>>(sorted, nodeoff, dx, db0, s1v);
    // layer 1 (4 threads/node + fused prep + 2-stage epilogue) -> h2hat (fp16)
    agg1_kernel<<<3125, 256, 0, stream>>>(sorted, nodeoff, db0, s1v,
                                          cw0, cb, lw, lb,
                                          cwr, cb + 16, lw + 256, lb + 16, h2hat);
    // layer 2 (unroll-8 gathers, fp16 h2hat reads, u32 edges) -> h3
    agg2_kernel<<<3125, 256, 0, stream>>>(sorted, nodeoff, h2hat, dinv,
                                          cwr + 256, cb + 32, lw + 512, lb + 32, h3);

    // fused attention pooling + final MLP (one wave per graph)
    poolfinal_kernel<<<N_GRAPHS, 64, 0, stream>>>(h3, batch, w1, b1, w2, b2, w3, b3, out);
}